// Round 1
// baseline (176.896 us; speedup 1.0000x reference)
//
#include <hip/hip_runtime.h>

// ---------- types & helpers ----------
typedef __attribute__((ext_vector_type(8))) short bf16x8;
typedef __attribute__((ext_vector_type(4))) float f32x4;

__device__ inline unsigned short f2bf(float f) {
  unsigned u = __builtin_bit_cast(unsigned, f);
  unsigned r = u + 0x7FFFu + ((u >> 16) & 1u);
  return (unsigned short)(r >> 16);
}

__device__ inline void gload_lds16(const unsigned short* g, unsigned short* l) {
  __builtin_amdgcn_global_load_lds(
      (const __attribute__((address_space(1))) unsigned int*)g,
      (__attribute__((address_space(3))) unsigned int*)l, 16, 0, 0);
}

// ---------- fp32 -> bf16 elementwise ----------
__global__ __launch_bounds__(256) void cvt_x_kernel(const float* __restrict__ in,
                                                    unsigned short* __restrict__ out, int n) {
  int stride = gridDim.x * blockDim.x;
  for (int i = blockIdx.x * blockDim.x + threadIdx.x; i * 4 < n; i += stride) {
    int idx = i * 4;
    float4 v = *(const float4*)&in[idx];
    ushort4 o;
    o.x = f2bf(v.x); o.y = f2bf(v.y); o.z = f2bf(v.z); o.w = f2bf(v.w);
    *(ushort4*)&out[idx] = o;
  }
}

// ---------- transpose + convert: in fp32 [R][C] -> out bf16 [C][R] ----------
__global__ __launch_bounds__(256) void transpose_cvt(const float* __restrict__ in,
                                                     unsigned short* __restrict__ out,
                                                     int R, int C) {
  __shared__ float t[32][33];
  int r0 = blockIdx.x * 32, c0 = blockIdx.y * 32;
  int tx = threadIdx.x & 31, ty = threadIdx.x >> 5;  // 8 rows of 32
  for (int r = ty; r < 32; r += 8)
    t[r][tx] = in[(size_t)(r0 + r) * C + c0 + tx];
  __syncthreads();
  for (int cc = ty; cc < 32; cc += 8)
    out[(size_t)(c0 + cc) * R + r0 + tx] = f2bf(t[tx][cc]);
}

// ---------- per-head V transpose: v[b*T+t][h*64+d] -> vt[(bh*64+d)][t] ----------
__global__ __launch_bounds__(256) void vt_kernel(const unsigned short* __restrict__ v,
                                                 unsigned short* __restrict__ vt) {
  int bh = blockIdx.x, tt = blockIdx.y, dt = blockIdx.z;
  int b = bh >> 4, h = bh & 15;
  __shared__ unsigned short tile[32][33];
  int tx = threadIdx.x & 31, ty = threadIdx.x >> 5;
  for (int r = ty; r < 32; r += 8)
    tile[r][tx] = v[(size_t)(b * 2048 + tt * 32 + r) * 1024 + h * 64 + dt * 32 + tx];
  __syncthreads();
  for (int r = ty; r < 32; r += 8)
    vt[((size_t)(bh * 64 + dt * 32 + r)) * 2048 + tt * 32 + tx] = tile[tx][r];
}

// ---------- GEMM: C[M][N] = A[M][K] * Bt[N][K]^T, bf16 in/out, fp32 accum ----------
// 128x128 tile, BK=32, 4 waves each computing 64x64 (4x4 of 16x16x32 MFMA)
__global__ __launch_bounds__(256) void gemm_bt(const unsigned short* __restrict__ A,
                                               const unsigned short* __restrict__ Bt,
                                               unsigned short* __restrict__ C,
                                               int M, int N, int K) {
  __shared__ unsigned short As[128 * 32];
  __shared__ unsigned short Bs[128 * 32];
  int m0 = blockIdx.x * 128, n0 = blockIdx.y * 128;
  int tid = threadIdx.x, w = tid >> 6, l = tid & 63;
  int lr = l & 15, lg = l >> 4;
  int wr = w >> 1, wc = w & 1;
  f32x4 acc[4][4] = {};

  for (int k0 = 0; k0 < K; k0 += 32) {
    __syncthreads();
#pragma unroll
    for (int it = 0; it < 2; ++it) {
      int c = w * 2 + it;                 // chunk 0..7, 1 KiB each
      int row = c * 16 + (l >> 2);
      int col = (l & 3) * 8;
      gload_lds16(&A[(size_t)(m0 + row) * K + k0 + col], &As[c * 512 + l * 8]);
      gload_lds16(&Bt[(size_t)(n0 + row) * K + k0 + col], &Bs[c * 512 + l * 8]);
    }
    __syncthreads();
    bf16x8 af[4], bfr[4];
#pragma unroll
    for (int m = 0; m < 4; ++m)
      af[m] = *(const bf16x8*)&As[(wr * 64 + m * 16 + lr) * 32 + lg * 8];
#pragma unroll
    for (int n = 0; n < 4; ++n)
      bfr[n] = *(const bf16x8*)&Bs[(wc * 64 + n * 16 + lr) * 32 + lg * 8];
#pragma unroll
    for (int m = 0; m < 4; ++m)
#pragma unroll
      for (int n = 0; n < 4; ++n)
        acc[m][n] = __builtin_amdgcn_mfma_f32_16x16x32_bf16(af[m], bfr[n], acc[m][n], 0, 0, 0);
  }

#pragma unroll
  for (int m = 0; m < 4; ++m)
#pragma unroll
    for (int n = 0; n < 4; ++n)
#pragma unroll
      for (int i = 0; i < 4; ++i)
        C[(size_t)(m0 + wr * 64 + m * 16 + lg * 4 + i) * N + n0 + wc * 64 + n * 16 + lr] =
            f2bf(acc[m][n][i]);
}

// ---------- flash attention (causal + key mask) ----------
// grid (bh=32, qt=32), 256 threads; wave w handles q rows qt*64 + w*16 .. +15
__global__ __launch_bounds__(256) void attn_kernel(const unsigned short* __restrict__ qg,
                                                   const unsigned short* __restrict__ kg,
                                                   const unsigned short* __restrict__ vtg,
                                                   const int* __restrict__ maskg,
                                                   float* __restrict__ outg) {
  const int bh = blockIdx.x, qt = blockIdx.y;
  const int b = bh >> 4, h = bh & 15;
  const int tid = threadIdx.x, w = tid >> 6, l = tid & 63;
  const int lr = l & 15, lg = l >> 4;

  __shared__ unsigned short Ks[64 * 72];     // [key][d], stride 72 (144B rows, 16B aligned)
  __shared__ unsigned short Vs[64 * 72];     // [d][key]
  __shared__ unsigned short Ps[4][16 * 72];  // per-wave P tile [qrow][key]

  const int qrow0 = qt * 64 + w * 16;
  bf16x8 qf[2];
#pragma unroll
  for (int s = 0; s < 2; ++s)
    qf[s] = *(const bf16x8*)&qg[(size_t)(b * 2048 + qrow0 + lr) * 1024 + h * 64 + s * 32 + lg * 8];

  f32x4 acc[4] = {};
  float m_i[4], l_i[4];
#pragma unroll
  for (int i = 0; i < 4; ++i) { m_i[i] = -1e30f; l_i[i] = 0.f; }

  for (int kt = 0; kt <= qt; ++kt) {
    __syncthreads();
#pragma unroll
    for (int it = 0; it < 2; ++it) {
      int slot = it * 256 + tid;          // 512 slots of 8 elems over a 64x64 tile
      int row = slot >> 3, c8 = (slot & 7) * 8;
      *(bf16x8*)&Ks[row * 72 + c8] =
          *(const bf16x8*)&kg[(size_t)(b * 2048 + kt * 64 + row) * 1024 + h * 64 + c8];
      *(bf16x8*)&Vs[row * 72 + c8] =
          *(const bf16x8*)&vtg[((size_t)(bh * 64 + row)) * 2048 + kt * 64 + c8];
    }
    __syncthreads();

    // S = Q K^T  (D[q][key]; C-layout: col=key=lr, row=lg*4+i)
    f32x4 s[4];
#pragma unroll
    for (int n = 0; n < 4; ++n) {
      f32x4 z = {};
#pragma unroll
      for (int ks = 0; ks < 2; ++ks) {
        bf16x8 kf = *(const bf16x8*)&Ks[(n * 16 + lr) * 72 + ks * 32 + lg * 8];
        z = __builtin_amdgcn_mfma_f32_16x16x32_bf16(qf[ks], kf, z, 0, 0, 0);
      }
      s[n] = z;
    }

    // mask + scale + online softmax
    float p[4][4];
    float mx[4] = {-1e30f, -1e30f, -1e30f, -1e30f};
#pragma unroll
    for (int n = 0; n < 4; ++n) {
      int key = kt * 64 + n * 16 + lr;
      bool keyok = (maskg[b * 2048 + key] != 0);
#pragma unroll
      for (int i = 0; i < 4; ++i) {
        int qrow = qrow0 + lg * 4 + i;
        float v = s[n][i] * 0.125f;
        v = (keyok && key <= qrow) ? v : -1e30f;
        p[n][i] = v;
        mx[i] = fmaxf(mx[i], v);
      }
    }
#pragma unroll
    for (int i = 0; i < 4; ++i)
#pragma unroll
      for (int off = 1; off < 16; off <<= 1)
        mx[i] = fmaxf(mx[i], __shfl_xor(mx[i], off, 64));

    float scale[4], rs[4];
#pragma unroll
    for (int i = 0; i < 4; ++i) {
      float mn = fmaxf(m_i[i], mx[i]);
      scale[i] = __expf(m_i[i] - mn);
      m_i[i] = mn;
      rs[i] = 0.f;
    }
#pragma unroll
    for (int n = 0; n < 4; ++n)
#pragma unroll
      for (int i = 0; i < 4; ++i) {
        float e = __expf(p[n][i] - m_i[i]);
        p[n][i] = e;
        rs[i] += e;
      }
#pragma unroll
    for (int i = 0; i < 4; ++i) {
#pragma unroll
      for (int off = 1; off < 16; off <<= 1)
        rs[i] += __shfl_xor(rs[i], off, 64);
      l_i[i] = l_i[i] * scale[i] + rs[i];
    }
#pragma unroll
    for (int dt = 0; dt < 4; ++dt)
#pragma unroll
      for (int i = 0; i < 4; ++i) acc[dt][i] *= scale[i];

    // P (C-layout) -> per-wave LDS -> A-fragments
#pragma unroll
    for (int n = 0; n < 4; ++n)
#pragma unroll
      for (int i = 0; i < 4; ++i)
        Ps[w][(lg * 4 + i) * 72 + n * 16 + lr] = f2bf(p[n][i]);
    __syncthreads();  // uniform trip count across block; also fences Ps RAW

    // O += P V
#pragma unroll
    for (int ks = 0; ks < 2; ++ks) {
      bf16x8 pf = *(const bf16x8*)&Ps[w][lr * 72 + ks * 32 + lg * 8];
#pragma unroll
      for (int dt = 0; dt < 4; ++dt) {
        bf16x8 vf = *(const bf16x8*)&Vs[(dt * 16 + lr) * 72 + ks * 32 + lg * 8];
        acc[dt] = __builtin_amdgcn_mfma_f32_16x16x32_bf16(pf, vf, acc[dt], 0, 0, 0);
      }
    }
  }

  float inv[4];
#pragma unroll
  for (int i = 0; i < 4; ++i) inv[i] = 1.f / l_i[i];
#pragma unroll
  for (int dt = 0; dt < 4; ++dt)
#pragma unroll
    for (int i = 0; i < 4; ++i)
      outg[(size_t)(b * 2048 + qrow0 + lg * 4 + i) * 1024 + h * 64 + dt * 16 + lr] =
          acc[dt][i] * inv[i];
}

// ---------- launch ----------
extern "C" void kernel_launch(void* const* d_in, const int* in_sizes, int n_in,
                              void* d_out, int out_size, void* d_ws, size_t ws_size,
                              hipStream_t stream) {
  const float* x    = (const float*)d_in[0];
  const int*   mask = (const int*)d_in[1];
  const float* w_q  = (const float*)d_in[2];
  const float* w_d  = (const float*)d_in[3];
  const float* w_k  = (const float*)d_in[4];
  const float* w_v  = (const float*)d_in[5];
  float* out = (float*)d_out;

  char* ws = (char*)d_ws;
  size_t off = 0;
  auto alloc = [&](size_t elems) {
    unsigned short* p = (unsigned short*)(ws + off);
    off += ((elems * 2 + 255) & ~(size_t)255);
    return p;
  };
  unsigned short* x_bf = alloc(4194304);   // [4096][1024]
  unsigned short* wqt  = alloc(1048576);   // [1024][1024] (N,K)
  unsigned short* wdt  = alloc(131072);    // [128][1024]
  unsigned short* wkt  = alloc(131072);    // [1024][128]
  unsigned short* wvt  = alloc(131072);    // [1024][128]
  unsigned short* q_bf = alloc(4194304);   // [4096][1024]
  unsigned short* lat  = alloc(524288);    // [4096][128]
  unsigned short* k_bf = alloc(4194304);   // [4096][1024]
  unsigned short* v_bf = alloc(4194304);   // [4096][1024]
  unsigned short* vt   = alloc(4194304);   // [32][64][2048]

  cvt_x_kernel<<<1024, 256, 0, stream>>>(x, x_bf, 4194304);
  transpose_cvt<<<dim3(32, 32), 256, 0, stream>>>(w_q, wqt, 1024, 1024);
  transpose_cvt<<<dim3(32, 4), 256, 0, stream>>>(w_d, wdt, 1024, 128);
  transpose_cvt<<<dim3(4, 32), 256, 0, stream>>>(w_k, wkt, 128, 1024);
  transpose_cvt<<<dim3(4, 32), 256, 0, stream>>>(w_v, wvt, 128, 1024);

  gemm_bt<<<dim3(32, 8), 256, 0, stream>>>(x_bf, wqt, q_bf, 4096, 1024, 1024);
  gemm_bt<<<dim3(32, 1), 256, 0, stream>>>(x_bf, wdt, lat, 4096, 128, 1024);
  gemm_bt<<<dim3(32, 8), 256, 0, stream>>>(lat, wkt, k_bf, 4096, 1024, 128);
  gemm_bt<<<dim3(32, 8), 256, 0, stream>>>(lat, wvt, v_bf, 4096, 1024, 128);

  vt_kernel<<<dim3(32, 64, 2), 256, 0, stream>>>(v_bf, vt);
  attn_kernel<<<dim3(32, 32), 256, 0, stream>>>(q_bf, k_bf, vt, mask, out);
}

// Round 2
// 137.021 us; speedup vs baseline: 1.2910x; 1.2910x over previous
//
#include <hip/hip_runtime.h>

// ---------- types & helpers ----------
typedef __attribute__((ext_vector_type(8))) short bf16x8;
typedef __attribute__((ext_vector_type(4))) float f32x4;

__device__ inline unsigned short f2bf(float f) {
  unsigned u = __builtin_bit_cast(unsigned, f);
  unsigned r = u + 0x7FFFu + ((u >> 16) & 1u);
  return (unsigned short)(r >> 16);
}
__device__ inline float bf2f(unsigned short s) {
  unsigned u = ((unsigned)s) << 16;
  return __builtin_bit_cast(float, u);
}

__device__ inline void gload_lds16(const unsigned short* g, unsigned short* l) {
  __builtin_amdgcn_global_load_lds(
      (const __attribute__((address_space(1))) unsigned int*)g,
      (__attribute__((address_space(3))) unsigned int*)l, 16, 0, 0);
}

// ---------- fp32 -> bf16 elementwise ----------
__global__ __launch_bounds__(256) void cvt_x_kernel(const float* __restrict__ in,
                                                    unsigned short* __restrict__ out, int n) {
  int stride = gridDim.x * blockDim.x;
  for (int i = blockIdx.x * blockDim.x + threadIdx.x; i * 4 < n; i += stride) {
    int idx = i * 4;
    float4 v = *(const float4*)&in[idx];
    ushort4 o;
    o.x = f2bf(v.x); o.y = f2bf(v.y); o.z = f2bf(v.z); o.w = f2bf(v.w);
    *(ushort4*)&out[idx] = o;
  }
}

// ---------- transpose + convert: in fp32 [R][C] -> out bf16 [C][R] (ld=R) ----------
__global__ __launch_bounds__(256) void transpose_cvt(const float* __restrict__ in,
                                                     unsigned short* __restrict__ out,
                                                     int R, int C) {
  __shared__ float t[32][33];
  int r0 = blockIdx.x * 32, c0 = blockIdx.y * 32;
  int tx = threadIdx.x & 31, ty = threadIdx.x >> 5;  // 8 rows of 32
  for (int r = ty; r < 32; r += 8)
    t[r][tx] = in[(size_t)(r0 + r) * C + c0 + tx];
  __syncthreads();
  for (int cc = ty; cc < 32; cc += 8)
    out[(size_t)(c0 + cc) * R + r0 + tx] = f2bf(t[tx][cc]);
}

// ---------- per-head V transpose: kv[b*T+t][1024+h*64+d] -> vt[(bh*64+d)][t] ----------
__global__ __launch_bounds__(256) void vt_kernel(const unsigned short* __restrict__ kv,
                                                 unsigned short* __restrict__ vt) {
  int bh = blockIdx.x, tt = blockIdx.y, dt = blockIdx.z;
  int b = bh >> 4, h = bh & 15;
  __shared__ unsigned short tile[32][33];
  int tx = threadIdx.x & 31, ty = threadIdx.x >> 5;
  for (int r = ty; r < 32; r += 8)
    tile[r][tx] = kv[(size_t)(b * 2048 + tt * 32 + r) * 2048 + 1024 + h * 64 + dt * 32 + tx];
  __syncthreads();
  for (int r = ty; r < 32; r += 8)
    vt[((size_t)(bh * 64 + dt * 32 + r)) * 2048 + tt * 32 + tx] = tile[tx][r];
}

// ---------- GEMM: C[M][N] = A[M][K] * Bt[N][K]^T, bf16 in/out, fp32 accum ----------
// 128x128 tile, BK=32, 4 waves each computing 64x64 (4x4 of 16x16x32 MFMA)
__global__ __launch_bounds__(256) void gemm_bt(const unsigned short* __restrict__ A, int lda,
                                               const unsigned short* __restrict__ Bt, int ldb,
                                               unsigned short* __restrict__ C, int ldc,
                                               int K) {
  __shared__ unsigned short As[128 * 32];
  __shared__ unsigned short Bs[128 * 32];
  int m0 = blockIdx.x * 128, n0 = blockIdx.y * 128;
  int tid = threadIdx.x, w = tid >> 6, l = tid & 63;
  int lr = l & 15, lg = l >> 4;
  int wr = w >> 1, wc = w & 1;
  f32x4 acc[4][4] = {};

  for (int k0 = 0; k0 < K; k0 += 32) {
    __syncthreads();
#pragma unroll
    for (int it = 0; it < 2; ++it) {
      int c = w * 2 + it;                 // chunk 0..7, 1 KiB each
      int row = c * 16 + (l >> 2);
      int col = (l & 3) * 8;
      gload_lds16(&A[(size_t)(m0 + row) * lda + k0 + col], &As[c * 512 + l * 8]);
      gload_lds16(&Bt[(size_t)(n0 + row) * ldb + k0 + col], &Bs[c * 512 + l * 8]);
    }
    __syncthreads();
    bf16x8 af[4], bfr[4];
#pragma unroll
    for (int m = 0; m < 4; ++m)
      af[m] = *(const bf16x8*)&As[(wr * 64 + m * 16 + lr) * 32 + lg * 8];
#pragma unroll
    for (int n = 0; n < 4; ++n)
      bfr[n] = *(const bf16x8*)&Bs[(wc * 64 + n * 16 + lr) * 32 + lg * 8];
#pragma unroll
    for (int m = 0; m < 4; ++m)
#pragma unroll
      for (int n = 0; n < 4; ++n)
        acc[m][n] = __builtin_amdgcn_mfma_f32_16x16x32_bf16(af[m], bfr[n], acc[m][n], 0, 0, 0);
  }

#pragma unroll
  for (int m = 0; m < 4; ++m)
#pragma unroll
    for (int n = 0; n < 4; ++n)
#pragma unroll
      for (int i = 0; i < 4; ++i)
        C[(size_t)(m0 + wr * 64 + m * 16 + lg * 4 + i) * ldc + n0 + wc * 64 + n * 16 + lr] =
            f2bf(acc[m][n][i]);
}

// ---------- flash attention (causal + key mask) ----------
// grid (bh=32, pair=16), 256 threads. Block handles qt = pair and qt = 31-pair
// (balanced 33 K-tile units per block). Wave w owns q rows qt*64 + w*16 .. +15.
__global__ __launch_bounds__(256) void attn_kernel(const unsigned short* __restrict__ qg,
                                                   const unsigned short* __restrict__ kvg,
                                                   const unsigned short* __restrict__ vtg,
                                                   const int* __restrict__ maskg,
                                                   float* __restrict__ outg) {
  const int bh = blockIdx.x, pr = blockIdx.y;
  const int b = bh >> 4, h = bh & 15;
  const int tid = threadIdx.x, w = tid >> 6, l = tid & 63;
  const int lr = l & 15, lg = l >> 4;

  __shared__ unsigned short Ks[64 * 72];     // [key][d], stride 72 (2-way banks on b128)
  __shared__ unsigned short Vs[64 * 72];     // [d][key]
  __shared__ unsigned short Ps[4][16 * 72];  // per-wave P tile [qrow][key]

  for (int pp = 0; pp < 2; ++pp) {
    const int qt = pp ? 31 - pr : pr;
    const int qrow0 = qt * 64 + w * 16;

    // q fragments, pre-scaled by 1/sqrt(dh)=0.125 (exact in bf16)
    bf16x8 qf[2];
#pragma unroll
    for (int s = 0; s < 2; ++s) {
      bf16x8 raw = *(const bf16x8*)&qg[(size_t)(b * 2048 + qrow0 + lr) * 1152 + h * 64 + s * 32 + lg * 8];
#pragma unroll
      for (int j = 0; j < 8; ++j)
        raw[j] = (short)f2bf(bf2f((unsigned short)raw[j]) * 0.125f);
      qf[s] = raw;
    }

    f32x4 acc[4] = {};
    float m_i[4], l_i[4];
#pragma unroll
    for (int i = 0; i < 4; ++i) { m_i[i] = -1e30f; l_i[i] = 0.f; }

    // prologue: stage tile 0
    bf16x8 kreg[2], vreg[2];
#pragma unroll
    for (int it = 0; it < 2; ++it) {
      int slot = it * 256 + tid, row = slot >> 3, c8 = (slot & 7) * 8;
      kreg[it] = *(const bf16x8*)&kvg[(size_t)(b * 2048 + row) * 2048 + h * 64 + c8];
      vreg[it] = *(const bf16x8*)&vtg[((size_t)(bh * 64 + row)) * 2048 + c8];
    }
#pragma unroll
    for (int it = 0; it < 2; ++it) {
      int slot = it * 256 + tid, row = slot >> 3, c8 = (slot & 7) * 8;
      *(bf16x8*)&Ks[row * 72 + c8] = kreg[it];
      *(bf16x8*)&Vs[row * 72 + c8] = vreg[it];
    }
    __syncthreads();

    for (int kt = 0; kt <= qt; ++kt) {
      // T14: issue next tile's global loads now; ds_write after the post-PV barrier
      if (kt < qt) {
#pragma unroll
        for (int it = 0; it < 2; ++it) {
          int slot = it * 256 + tid, row = slot >> 3, c8 = (slot & 7) * 8;
          kreg[it] = *(const bf16x8*)&kvg[(size_t)(b * 2048 + (kt + 1) * 64 + row) * 2048 + h * 64 + c8];
          vreg[it] = *(const bf16x8*)&vtg[((size_t)(bh * 64 + row)) * 2048 + (kt + 1) * 64 + c8];
        }
      }

      // S = Q K^T  (C-layout: col=key=lr, row=lg*4+i)
      f32x4 s[4];
      __builtin_amdgcn_s_setprio(1);
#pragma unroll
      for (int n = 0; n < 4; ++n) {
        f32x4 z = {};
#pragma unroll
        for (int ks = 0; ks < 2; ++ks) {
          bf16x8 kf = *(const bf16x8*)&Ks[(n * 16 + lr) * 72 + ks * 32 + lg * 8];
          z = __builtin_amdgcn_mfma_f32_16x16x32_bf16(qf[ks], kf, z, 0, 0, 0);
        }
        s[n] = z;
      }
      __builtin_amdgcn_s_setprio(0);

      // mask + online softmax
      float p[4][4];
      float mx[4] = {-1e30f, -1e30f, -1e30f, -1e30f};
#pragma unroll
      for (int n = 0; n < 4; ++n) {
        int key = kt * 64 + n * 16 + lr;
        bool keyok = (maskg[b * 2048 + key] != 0);
#pragma unroll
        for (int i = 0; i < 4; ++i) {
          int qrow = qrow0 + lg * 4 + i;
          float v = s[n][i];
          v = (keyok && key <= qrow) ? v : -1e30f;
          p[n][i] = v;
          mx[i] = fmaxf(mx[i], v);
        }
      }
#pragma unroll
      for (int i = 0; i < 4; ++i)
#pragma unroll
        for (int off = 1; off < 16; off <<= 1)
          mx[i] = fmaxf(mx[i], __shfl_xor(mx[i], off, 64));

      float scale[4], rs[4];
#pragma unroll
      for (int i = 0; i < 4; ++i) {
        float mn = fmaxf(m_i[i], mx[i]);
        scale[i] = __expf(m_i[i] - mn);
        m_i[i] = mn;
        rs[i] = 0.f;
      }
#pragma unroll
      for (int n = 0; n < 4; ++n)
#pragma unroll
        for (int i = 0; i < 4; ++i) {
          float e = __expf(p[n][i] - m_i[i]);
          p[n][i] = e;
          rs[i] += e;
        }
#pragma unroll
      for (int i = 0; i < 4; ++i) {
#pragma unroll
        for (int off = 1; off < 16; off <<= 1)
          rs[i] += __shfl_xor(rs[i], off, 64);
        l_i[i] = l_i[i] * scale[i] + rs[i];
      }
#pragma unroll
      for (int dt = 0; dt < 4; ++dt)
#pragma unroll
        for (int i = 0; i < 4; ++i) acc[dt][i] *= scale[i];

      // P (C-layout) -> per-wave LDS -> A-fragments (wave-synchronous, no barrier)
#pragma unroll
      for (int n = 0; n < 4; ++n)
#pragma unroll
        for (int i = 0; i < 4; ++i)
          Ps[w][(lg * 4 + i) * 72 + n * 16 + lr] = f2bf(p[n][i]);
      asm volatile("s_waitcnt lgkmcnt(0)" ::: "memory");

      // O += P V
      __builtin_amdgcn_s_setprio(1);
#pragma unroll
      for (int ks = 0; ks < 2; ++ks) {
        bf16x8 pf = *(const bf16x8*)&Ps[w][lr * 72 + ks * 32 + lg * 8];
#pragma unroll
        for (int dt = 0; dt < 4; ++dt) {
          bf16x8 vf = *(const bf16x8*)&Vs[(dt * 16 + lr) * 72 + ks * 32 + lg * 8];
          acc[dt] = __builtin_amdgcn_mfma_f32_16x16x32_bf16(pf, vf, acc[dt], 0, 0, 0);
        }
      }
      __builtin_amdgcn_s_setprio(0);

      __syncthreads();  // all LDS reads of this tile done
      if (kt < qt) {
#pragma unroll
        for (int it = 0; it < 2; ++it) {
          int slot = it * 256 + tid, row = slot >> 3, c8 = (slot & 7) * 8;
          *(bf16x8*)&Ks[row * 72 + c8] = kreg[it];
          *(bf16x8*)&Vs[row * 72 + c8] = vreg[it];
        }
        __syncthreads();
      }
    }

    float inv[4];
#pragma unroll
    for (int i = 0; i < 4; ++i) inv[i] = 1.f / l_i[i];
#pragma unroll
    for (int dt = 0; dt < 4; ++dt)
#pragma unroll
      for (int i = 0; i < 4; ++i)
        outg[(size_t)(b * 2048 + qrow0 + lg * 4 + i) * 1024 + h * 64 + dt * 16 + lr] =
            acc[dt][i] * inv[i];
  }
}

// ---------- launch ----------
extern "C" void kernel_launch(void* const* d_in, const int* in_sizes, int n_in,
                              void* d_out, int out_size, void* d_ws, size_t ws_size,
                              hipStream_t stream) {
  const float* x    = (const float*)d_in[0];
  const int*   mask = (const int*)d_in[1];
  const float* w_q  = (const float*)d_in[2];
  const float* w_d  = (const float*)d_in[3];
  const float* w_k  = (const float*)d_in[4];
  const float* w_v  = (const float*)d_in[5];
  float* out = (float*)d_out;

  char* ws = (char*)d_ws;
  size_t off = 0;
  auto alloc = [&](size_t elems) {
    unsigned short* p = (unsigned short*)(ws + off);
    off += ((elems * 2 + 255) & ~(size_t)255);
    return p;
  };
  unsigned short* x_bf = alloc(4194304);            // [4096][1024]
  unsigned short* wqdt = alloc(1152 * 1024);        // [1152][1024]: rows 0..1023 wq^T, 1024.. wd^T
  unsigned short* wkvt = alloc(2048 * 128);         // [2048][128]:  rows 0..1023 wk^T, 1024.. wv^T
  unsigned short* qlat = alloc(4096 * 1152);        // [4096][1152]: q | latent
  unsigned short* kv   = alloc(4096 * 2048);        // [4096][2048]: k | v
  unsigned short* vt   = alloc(4194304);            // [32][64][2048]

  cvt_x_kernel<<<1024, 256, 0, stream>>>(x, x_bf, 4194304);
  transpose_cvt<<<dim3(32, 32), 256, 0, stream>>>(w_q, wqdt, 1024, 1024);
  transpose_cvt<<<dim3(32, 4), 256, 0, stream>>>(w_d, wqdt + 1024 * 1024, 1024, 128);
  transpose_cvt<<<dim3(4, 32), 256, 0, stream>>>(w_k, wkvt, 128, 1024);
  transpose_cvt<<<dim3(4, 32), 256, 0, stream>>>(w_v, wkvt + 1024 * 128, 128, 1024);

  gemm_bt<<<dim3(32, 9), 256, 0, stream>>>(x_bf, 1024, wqdt, 1024, qlat, 1152, 1024);
  gemm_bt<<<dim3(32, 16), 256, 0, stream>>>(qlat + 1024, 1152, wkvt, 128, kv, 2048, 128);

  vt_kernel<<<dim3(32, 64, 2), 256, 0, stream>>>(kv, vt);
  attn_kernel<<<dim3(32, 16), 256, 0, stream>>>(qlat, kv, vt, mask, out);
}

// Round 4
// 112.080 us; speedup vs baseline: 1.5783x; 1.2225x over previous
//
#include <hip/hip_runtime.h>

// ---------- types & helpers ----------
typedef __attribute__((ext_vector_type(8))) short bf16x8;
typedef __attribute__((ext_vector_type(4))) float f32x4;

__device__ inline unsigned short f2bf(float f) {
  unsigned u = __builtin_bit_cast(unsigned, f);
  unsigned r = u + 0x7FFFu + ((u >> 16) & 1u);
  return (unsigned short)(r >> 16);
}
__device__ inline float bf2f(unsigned short s) {
  unsigned u = ((unsigned)s) << 16;
  return __builtin_bit_cast(float, u);
}
__device__ inline float fexp2(float x) { return __builtin_amdgcn_exp2f(x); }

__device__ inline void gload_lds16(const unsigned short* g, unsigned short* l) {
  __builtin_amdgcn_global_load_lds(
      (const __attribute__((address_space(1))) unsigned int*)g,
      (__attribute__((address_space(3))) unsigned int*)l, 16, 0, 0);
}

// ---------- fused preprocessing: x->bf16, 4 weight transposes, mask bias ----------
__global__ __launch_bounds__(256) void prep_kernel(
    const float* __restrict__ x, const int* __restrict__ mask,
    const float* __restrict__ w_q, const float* __restrict__ w_d,
    const float* __restrict__ w_k, const float* __restrict__ w_v,
    unsigned short* __restrict__ x_bf, unsigned short* __restrict__ wqdt,
    unsigned short* __restrict__ wkvt, float* __restrict__ bias) {
  int bid = blockIdx.x;
  if (bid < 1024) {  // x fp32 -> bf16, 4096 elems/block
    int base = bid * 4096 + threadIdx.x * 4;
#pragma unroll
    for (int it = 0; it < 4; ++it) {
      int idx = base + it * 1024;
      float4 v = *(const float4*)&x[idx];
      ushort4 o;
      o.x = f2bf(v.x); o.y = f2bf(v.y); o.z = f2bf(v.z); o.w = f2bf(v.w);
      *(ushort4*)&x_bf[idx] = o;
    }
    return;
  }
  int tb = bid - 1024;
  if (tb >= 1408) {  // mask -> additive bias
    int i = (tb - 1408) * 256 + threadIdx.x;
    bias[i] = mask[i] ? 0.0f : -1e30f;
    return;
  }
  const float* in; unsigned short* out; int R, C, tr, tc;
  if (tb < 1024)      { in = w_q; out = wqdt;               R = 1024; C = 1024; tr = tb >> 5; tc = tb & 31; }
  else if (tb < 1152) { int t2 = tb - 1024; in = w_d; out = wqdt + 1024 * 1024; R = 1024; C = 128; tr = t2 >> 2; tc = t2 & 3; }
  else if (tb < 1280) { int t2 = tb - 1152; in = w_k; out = wkvt;               R = 128; C = 1024; tr = t2 >> 5; tc = t2 & 31; }
  else                { int t2 = tb - 1280; in = w_v; out = wkvt + 1024 * 128;  R = 128; C = 1024; tr = t2 >> 5; tc = t2 & 31; }
  __shared__ float t[32][33];
  int r0 = tr * 32, c0 = tc * 32;
  int tx = threadIdx.x & 31, ty = threadIdx.x >> 5;
  for (int r = ty; r < 32; r += 8)
    t[r][tx] = in[(size_t)(r0 + r) * C + c0 + tx];
  __syncthreads();
  for (int cc = ty; cc < 32; cc += 8)
    out[(size_t)(c0 + cc) * R + r0 + tx] = f2bf(t[tx][cc]);
}

// ---------- per-head V transpose: kv[b*T+t][1024+h*64+d] -> vt[(bh*64+d)][t] ----------
__global__ __launch_bounds__(256) void vt_kernel(const unsigned short* __restrict__ kv,
                                                 unsigned short* __restrict__ vt) {
  int bh = blockIdx.x, tt = blockIdx.y, dt = blockIdx.z;
  int b = bh >> 4, h = bh & 15;
  __shared__ unsigned short tile[32][33];
  int tx = threadIdx.x & 31, ty = threadIdx.x >> 5;
  for (int r = ty; r < 32; r += 8)
    tile[r][tx] = kv[(size_t)(b * 2048 + tt * 32 + r) * 2048 + 1024 + h * 64 + dt * 32 + tx];
  __syncthreads();
  for (int r = ty; r < 32; r += 8)
    vt[((size_t)(bh * 64 + dt * 32 + r)) * 2048 + tt * 32 + tx] = tile[tx][r];
}

// ---------- GEMM: C[M][N] = A[M][K] * Bt[N][K]^T, bf16 in/out, fp32 accum ----------
__global__ __launch_bounds__(256) void gemm_bt(const unsigned short* __restrict__ A, int lda,
                                               const unsigned short* __restrict__ Bt, int ldb,
                                               unsigned short* __restrict__ C, int ldc,
                                               int K) {
  __shared__ unsigned short As[128 * 32];
  __shared__ unsigned short Bs[128 * 32];
  int m0 = blockIdx.x * 128, n0 = blockIdx.y * 128;
  int tid = threadIdx.x, w = tid >> 6, l = tid & 63;
  int lr = l & 15, lg = l >> 4;
  int wr = w >> 1, wc = w & 1;
  f32x4 acc[4][4] = {};

  for (int k0 = 0; k0 < K; k0 += 32) {
    __syncthreads();
#pragma unroll
    for (int it = 0; it < 2; ++it) {
      int c = w * 2 + it;
      int row = c * 16 + (l >> 2);
      int col = (l & 3) * 8;
      gload_lds16(&A[(size_t)(m0 + row) * lda + k0 + col], &As[c * 512 + l * 8]);
      gload_lds16(&Bt[(size_t)(n0 + row) * ldb + k0 + col], &Bs[c * 512 + l * 8]);
    }
    __syncthreads();
    bf16x8 af[4], bfr[4];
#pragma unroll
    for (int m = 0; m < 4; ++m)
      af[m] = *(const bf16x8*)&As[(wr * 64 + m * 16 + lr) * 32 + lg * 8];
#pragma unroll
    for (int n = 0; n < 4; ++n)
      bfr[n] = *(const bf16x8*)&Bs[(wc * 64 + n * 16 + lr) * 32 + lg * 8];
    __builtin_amdgcn_s_setprio(1);
#pragma unroll
    for (int m = 0; m < 4; ++m)
#pragma unroll
      for (int n = 0; n < 4; ++n)
        acc[m][n] = __builtin_amdgcn_mfma_f32_16x16x32_bf16(af[m], bfr[n], acc[m][n], 0, 0, 0);
    __builtin_amdgcn_s_setprio(0);
  }

#pragma unroll
  for (int m = 0; m < 4; ++m)
#pragma unroll
    for (int n = 0; n < 4; ++n)
#pragma unroll
      for (int i = 0; i < 4; ++i)
        C[(size_t)(m0 + wr * 64 + m * 16 + lg * 4 + i) * ldc + n0 + wc * 64 + n * 16 + lr] =
            f2bf(acc[m][n][i]);
}

// ---------- flash attention (causal + key-mask bias), exp2 domain ----------
// grid (bh=32, y=32), qt = 31 - y (heaviest first). 4 waves, wave w owns 16 q rows.
__global__ __launch_bounds__(256) void attn_kernel(const unsigned short* __restrict__ qg,
                                                   const unsigned short* __restrict__ kvg,
                                                   const unsigned short* __restrict__ vtg,
                                                   const float* __restrict__ biasg,
                                                   float* __restrict__ outg) {
  const int bh = blockIdx.x, qt = 31 - blockIdx.y;
  const int b = bh >> 4, h = bh & 15;
  const int tid = threadIdx.x, w = tid >> 6, l = tid & 63;
  const int lr = l & 15, lg = l >> 4;

  __shared__ unsigned short Ks[64 * 72];     // [key][d]
  __shared__ unsigned short Vs[64 * 72];     // [d][key]
  __shared__ unsigned short Ps[4][16 * 72];  // per-wave P tile [qrow][key]

  const int qrow0 = qt * 64 + w * 16;
  const float QSCALE = 0.125f * 1.44269504089f;  // 1/sqrt(dh) * log2(e)

  bf16x8 qf[2];
#pragma unroll
  for (int s = 0; s < 2; ++s) {
    bf16x8 raw = *(const bf16x8*)&qg[(size_t)(b * 2048 + qrow0 + lr) * 1152 + h * 64 + s * 32 + lg * 8];
#pragma unroll
    for (int j = 0; j < 8; ++j)
      raw[j] = (short)f2bf(bf2f((unsigned short)raw[j]) * QSCALE);
    qf[s] = raw;
  }

  f32x4 acc[4] = {};
  float m_i[4], l_i[4];
#pragma unroll
  for (int i = 0; i < 4; ++i) { m_i[i] = -1e30f; l_i[i] = 0.f; }

  // prologue: stage tile 0
  bf16x8 kreg[2], vreg[2];
#pragma unroll
  for (int it = 0; it < 2; ++it) {
    int slot = it * 256 + tid, row = slot >> 3, c8 = (slot & 7) * 8;
    kreg[it] = *(const bf16x8*)&kvg[(size_t)(b * 2048 + row) * 2048 + h * 64 + c8];
    vreg[it] = *(const bf16x8*)&vtg[((size_t)(bh * 64 + row)) * 2048 + c8];
  }
#pragma unroll
  for (int it = 0; it < 2; ++it) {
    int slot = it * 256 + tid, row = slot >> 3, c8 = (slot & 7) * 8;
    *(bf16x8*)&Ks[row * 72 + c8] = kreg[it];
    *(bf16x8*)&Vs[row * 72 + c8] = vreg[it];
  }
  __syncthreads();

  for (int kt = 0; kt <= qt; ++kt) {
    // T14 async-stage: issue next tile's global loads now, ds_write after post-PV barrier
    if (kt < qt) {
#pragma unroll
      for (int it = 0; it < 2; ++it) {
        int slot = it * 256 + tid, row = slot >> 3, c8 = (slot & 7) * 8;
        kreg[it] = *(const bf16x8*)&kvg[(size_t)(b * 2048 + (kt + 1) * 64 + row) * 2048 + h * 64 + c8];
        vreg[it] = *(const bf16x8*)&vtg[((size_t)(bh * 64 + row)) * 2048 + (kt + 1) * 64 + c8];
      }
    }

    // S = Q K^T (log2 domain); C-layout: col=key=lr, row=lg*4+i
    f32x4 s[4];
    __builtin_amdgcn_s_setprio(1);
#pragma unroll
    for (int n = 0; n < 4; ++n) {
      f32x4 z = {};
#pragma unroll
      for (int ks = 0; ks < 2; ++ks) {
        bf16x8 kf = *(const bf16x8*)&Ks[(n * 16 + lr) * 72 + ks * 32 + lg * 8];
        z = __builtin_amdgcn_mfma_f32_16x16x32_bf16(qf[ks], kf, z, 0, 0, 0);
      }
      s[n] = z;
    }
    __builtin_amdgcn_s_setprio(0);

    // key-mask bias + (diagonal only) causal mask; per-row max
    float bs[4];
#pragma unroll
    for (int n = 0; n < 4; ++n) bs[n] = biasg[b * 2048 + kt * 64 + n * 16 + lr];

    float p[4][4];
    float mx[4] = {-1e30f, -1e30f, -1e30f, -1e30f};
    if (kt == qt) {
#pragma unroll
      for (int n = 0; n < 4; ++n) {
        int key = kt * 64 + n * 16 + lr;
#pragma unroll
        for (int i = 0; i < 4; ++i) {
          float v = s[n][i] + bs[n];
          v = (key <= qrow0 + lg * 4 + i) ? v : -1e30f;
          p[n][i] = v;
          mx[i] = fmaxf(mx[i], v);
        }
      }
    } else {
#pragma unroll
      for (int n = 0; n < 4; ++n)
#pragma unroll
        for (int i = 0; i < 4; ++i) {
          float v = s[n][i] + bs[n];
          p[n][i] = v;
          mx[i] = fmaxf(mx[i], v);
        }
    }
#pragma unroll
    for (int i = 0; i < 4; ++i)
#pragma unroll
      for (int off = 1; off < 16; off <<= 1)
        mx[i] = fmaxf(mx[i], __shfl_xor(mx[i], off, 64));

    // T13 defer-rescale (THR=8 in log2 domain)
    float g = fmaxf(fmaxf(mx[0] - m_i[0], mx[1] - m_i[1]),
                    fmaxf(mx[2] - m_i[2], mx[3] - m_i[3]));
    if (__any(g > 8.0f)) {
#pragma unroll
      for (int i = 0; i < 4; ++i) {
        float mn = fmaxf(m_i[i], mx[i]);
        float sc = fexp2(m_i[i] - mn);
        m_i[i] = mn;
        l_i[i] *= sc;
#pragma unroll
        for (int dt = 0; dt < 4; ++dt) acc[dt][i] *= sc;
      }
    }

    float rs[4] = {0.f, 0.f, 0.f, 0.f};
#pragma unroll
    for (int n = 0; n < 4; ++n)
#pragma unroll
      for (int i = 0; i < 4; ++i) {
        float e = fexp2(p[n][i] - m_i[i]);
        p[n][i] = e;
        rs[i] += e;
      }
#pragma unroll
    for (int i = 0; i < 4; ++i) {
#pragma unroll
      for (int off = 1; off < 16; off <<= 1)
        rs[i] += __shfl_xor(rs[i], off, 64);
      l_i[i] += rs[i];
    }

    // P -> per-wave LDS (cvt_pk pairs), wave-synchronous
#pragma unroll
    for (int n = 0; n < 4; ++n)
#pragma unroll
      for (int i2 = 0; i2 < 4; i2 += 2) {
        unsigned rr;
        asm("v_cvt_pk_bf16_f32 %0, %1, %2" : "=v"(rr) : "v"(p[n][i2]), "v"(p[n][i2 + 1]));
        Ps[w][(lg * 4 + i2) * 72 + n * 16 + lr] = (unsigned short)rr;
        Ps[w][(lg * 4 + i2 + 1) * 72 + n * 16 + lr] = (unsigned short)(rr >> 16);
      }
    asm volatile("s_waitcnt lgkmcnt(0)" ::: "memory");

    // O += P V
    __builtin_amdgcn_s_setprio(1);
#pragma unroll
    for (int ks = 0; ks < 2; ++ks) {
      bf16x8 pf = *(const bf16x8*)&Ps[w][lr * 72 + ks * 32 + lg * 8];
#pragma unroll
      for (int dt = 0; dt < 4; ++dt) {
        bf16x8 vf = *(const bf16x8*)&Vs[(dt * 16 + lr) * 72 + ks * 32 + lg * 8];
        acc[dt] = __builtin_amdgcn_mfma_f32_16x16x32_bf16(pf, vf, acc[dt], 0, 0, 0);
      }
    }
    __builtin_amdgcn_s_setprio(0);

    __syncthreads();
    if (kt < qt) {
#pragma unroll
      for (int it = 0; it < 2; ++it) {
        int slot = it * 256 + tid, row = slot >> 3, c8 = (slot & 7) * 8;
        *(bf16x8*)&Ks[row * 72 + c8] = kreg[it];
        *(bf16x8*)&Vs[row * 72 + c8] = vreg[it];
      }
      __syncthreads();
    }
  }

  float inv[4];
#pragma unroll
  for (int i = 0; i < 4; ++i) inv[i] = 1.f / l_i[i];
#pragma unroll
  for (int dt = 0; dt < 4; ++dt)
#pragma unroll
    for (int i = 0; i < 4; ++i)
      outg[(size_t)(b * 2048 + qrow0 + lg * 4 + i) * 1024 + h * 64 + dt * 16 + lr] =
          acc[dt][i] * inv[i];
}

// ---------- launch ----------
extern "C" void kernel_launch(void* const* d_in, const int* in_sizes, int n_in,
                              void* d_out, int out_size, void* d_ws, size_t ws_size,
                              hipStream_t stream) {
  const float* x    = (const float*)d_in[0];
  const int*   mask = (const int*)d_in[1];
  const float* w_q  = (const float*)d_in[2];
  const float* w_d  = (const float*)d_in[3];
  const float* w_k  = (const float*)d_in[4];
  const float* w_v  = (const float*)d_in[5];
  float* out = (float*)d_out;

  char* ws = (char*)d_ws;
  size_t off = 0;
  auto alloc = [&](size_t elems) {
    unsigned short* p = (unsigned short*)(ws + off);
    off += ((elems * 2 + 255) & ~(size_t)255);
    return p;
  };
  unsigned short* x_bf = alloc(4194304);      // [4096][1024]
  unsigned short* wqdt = alloc(1152 * 1024);  // [1152][1024]
  unsigned short* wkvt = alloc(2048 * 128);   // [2048][128]
  unsigned short* qlat = alloc(4096 * 1152);  // [4096][1152]: q | latent
  unsigned short* kv   = alloc(4096 * 2048);  // [4096][2048]: k | v
  unsigned short* vt   = alloc(4194304);      // [32][64][2048]
  float* bias = (float*)alloc(8192);          // 4096 floats

  prep_kernel<<<2448, 256, 0, stream>>>(x, mask, w_q, w_d, w_k, w_v, x_bf, wqdt, wkvt, bias);

  gemm_bt<<<dim3(32, 9), 256, 0, stream>>>(x_bf, 1024, wqdt, 1024, qlat, 1152, 1024);
  gemm_bt<<<dim3(32, 16), 256, 0, stream>>>(qlat + 1024, 1152, wkvt, 128, kv, 2048, 128);

  vt_kernel<<<dim3(32, 64, 2), 256, 0, stream>>>(kv, vt);
  attn_kernel<<<dim3(32, 32), 256, 0, stream>>>(qlat, kv, vt, bias, out);
}

// Round 6
// 98.652 us; speedup vs baseline: 1.7931x; 1.1361x over previous
//
#include <hip/hip_runtime.h>

// ---------- types & helpers ----------
typedef __attribute__((ext_vector_type(8))) short bf16x8;
typedef __attribute__((ext_vector_type(4))) float f32x4;

__device__ inline unsigned short f2bf(float f) {
  unsigned u = __builtin_bit_cast(unsigned, f);
  unsigned r = u + 0x7FFFu + ((u >> 16) & 1u);
  return (unsigned short)(r >> 16);
}
__device__ inline float bf2f(unsigned short s) {
  unsigned u = ((unsigned)s) << 16;
  return __builtin_bit_cast(float, u);
}
__device__ inline float fexp2(float x) { return __builtin_amdgcn_exp2f(x); }

// DPP butterfly reduce over 16 contiguous lanes (row_ror 1,2,4,8)
template <int CTRL>
__device__ inline float dpp_max(float x) {
  int t = __builtin_amdgcn_update_dpp(0, __builtin_bit_cast(int, x), CTRL, 0xF, 0xF, true);
  return fmaxf(x, __builtin_bit_cast(float, t));
}
template <int CTRL>
__device__ inline float dpp_add(float x) {
  int t = __builtin_amdgcn_update_dpp(0, __builtin_bit_cast(int, x), CTRL, 0xF, 0xF, true);
  return x + __builtin_bit_cast(float, t);
}
__device__ inline float rowmax16(float x) {
  return dpp_max<0x128>(dpp_max<0x124>(dpp_max<0x122>(dpp_max<0x121>(x))));
}
__device__ inline float rowsum16(float x) {
  return dpp_add<0x128>(dpp_add<0x124>(dpp_add<0x122>(dpp_add<0x121>(x))));
}

__device__ inline void gload_lds16(const unsigned short* g, unsigned short* l) {
  __builtin_amdgcn_global_load_lds(
      (const __attribute__((address_space(1))) unsigned int*)g,
      (__attribute__((address_space(3))) unsigned int*)l, 16, 0, 0);
}

// ---------- fused preprocessing: x->bf16, 4 weight transposes, mask bias ----------
__global__ __launch_bounds__(256) void prep_kernel(
    const float* __restrict__ x, const int* __restrict__ mask,
    const float* __restrict__ w_q, const float* __restrict__ w_d,
    const float* __restrict__ w_k, const float* __restrict__ w_v,
    unsigned short* __restrict__ x_bf, unsigned short* __restrict__ wqdt,
    unsigned short* __restrict__ wkvt, float* __restrict__ bias) {
  int bid = blockIdx.x;
  if (bid < 1024) {  // x fp32 -> bf16, 4096 elems/block
    int base = bid * 4096 + threadIdx.x * 4;
#pragma unroll
    for (int it = 0; it < 4; ++it) {
      int idx = base + it * 1024;
      float4 v = *(const float4*)&x[idx];
      ushort4 o;
      o.x = f2bf(v.x); o.y = f2bf(v.y); o.z = f2bf(v.z); o.w = f2bf(v.w);
      *(ushort4*)&x_bf[idx] = o;
    }
    return;
  }
  int tb = bid - 1024;
  if (tb >= 1408) {  // mask -> additive bias
    int i = (tb - 1408) * 256 + threadIdx.x;
    bias[i] = mask[i] ? 0.0f : -1e30f;
    return;
  }
  const float* in; unsigned short* out; int R, C, tr, tc;
  if (tb < 1024)      { in = w_q; out = wqdt;               R = 1024; C = 1024; tr = tb >> 5; tc = tb & 31; }
  else if (tb < 1152) { int t2 = tb - 1024; in = w_d; out = wqdt + 1024 * 1024; R = 1024; C = 128; tr = t2 >> 2; tc = t2 & 3; }
  else if (tb < 1280) { int t2 = tb - 1152; in = w_k; out = wkvt;               R = 128; C = 1024; tr = t2 >> 5; tc = t2 & 31; }
  else                { int t2 = tb - 1280; in = w_v; out = wkvt + 1024 * 128;  R = 128; C = 1024; tr = t2 >> 5; tc = t2 & 31; }
  __shared__ float t[32][33];
  int r0 = tr * 32, c0 = tc * 32;
  int tx = threadIdx.x & 31, ty = threadIdx.x >> 5;
  for (int r = ty; r < 32; r += 8)
    t[r][tx] = in[(size_t)(r0 + r) * C + c0 + tx];
  __syncthreads();
  for (int cc = ty; cc < 32; cc += 8)
    out[(size_t)(c0 + cc) * R + r0 + tx] = f2bf(t[tx][cc]);
}

// ---------- per-head V transpose: kv[b*T+t][1024+h*64+d] -> vt[(bh*64+d)][t] ----------
__global__ __launch_bounds__(256) void vt_kernel(const unsigned short* __restrict__ kv,
                                                 unsigned short* __restrict__ vt) {
  int bh = blockIdx.x, tt = blockIdx.y, dt = blockIdx.z;
  int b = bh >> 4, h = bh & 15;
  __shared__ unsigned short tile[32][33];
  int tx = threadIdx.x & 31, ty = threadIdx.x >> 5;
  for (int r = ty; r < 32; r += 8)
    tile[r][tx] = kv[(size_t)(b * 2048 + tt * 32 + r) * 2048 + 1024 + h * 64 + dt * 32 + tx];
  __syncthreads();
  for (int r = ty; r < 32; r += 8)
    vt[((size_t)(bh * 64 + dt * 32 + r)) * 2048 + tt * 32 + tx] = tile[tx][r];
}

// ---------- GEMM: C[M][N] = A[M][K] * Bt[N][K]^T, bf16 in/out, fp32 accum ----------
__global__ __launch_bounds__(256) void gemm_bt(const unsigned short* __restrict__ A, int lda,
                                               const unsigned short* __restrict__ Bt, int ldb,
                                               unsigned short* __restrict__ C, int ldc,
                                               int K) {
  __shared__ unsigned short As[128 * 32];
  __shared__ unsigned short Bs[128 * 32];
  int m0 = blockIdx.x * 128, n0 = blockIdx.y * 128;
  int tid = threadIdx.x, w = tid >> 6, l = tid & 63;
  int lr = l & 15, lg = l >> 4;
  int wr = w >> 1, wc = w & 1;
  f32x4 acc[4][4] = {};

  for (int k0 = 0; k0 < K; k0 += 32) {
    __syncthreads();
#pragma unroll
    for (int it = 0; it < 2; ++it) {
      int c = w * 2 + it;
      int row = c * 16 + (l >> 2);
      int col = (l & 3) * 8;
      gload_lds16(&A[(size_t)(m0 + row) * lda + k0 + col], &As[c * 512 + l * 8]);
      gload_lds16(&Bt[(size_t)(n0 + row) * ldb + k0 + col], &Bs[c * 512 + l * 8]);
    }
    __syncthreads();
    bf16x8 af[4], bfr[4];
#pragma unroll
    for (int m = 0; m < 4; ++m)
      af[m] = *(const bf16x8*)&As[(wr * 64 + m * 16 + lr) * 32 + lg * 8];
#pragma unroll
    for (int n = 0; n < 4; ++n)
      bfr[n] = *(const bf16x8*)&Bs[(wc * 64 + n * 16 + lr) * 32 + lg * 8];
    __builtin_amdgcn_s_setprio(1);
#pragma unroll
    for (int m = 0; m < 4; ++m)
#pragma unroll
      for (int n = 0; n < 4; ++n)
        acc[m][n] = __builtin_amdgcn_mfma_f32_16x16x32_bf16(af[m], bfr[n], acc[m][n], 0, 0, 0);
    __builtin_amdgcn_s_setprio(0);
  }

#pragma unroll
  for (int m = 0; m < 4; ++m)
#pragma unroll
    for (int n = 0; n < 4; ++n)
#pragma unroll
      for (int i = 0; i < 4; ++i)
        C[(size_t)(m0 + wr * 64 + m * 16 + lg * 4 + i) * ldc + n0 + wc * 64 + n * 16 + lr] =
            f2bf(acc[m][n][i]);
}

// ---------- flash attention (causal + key-mask bias), exp2 domain, DPP reductions ----------
// grid (bh=32, y=32), qt = 31 - y (heaviest first). 4 waves, wave w owns 16 q rows.
__global__ __launch_bounds__(256) void attn_kernel(const unsigned short* __restrict__ qg,
                                                   const unsigned short* __restrict__ kvg,
                                                   const unsigned short* __restrict__ vtg,
                                                   const float* __restrict__ biasg,
                                                   float* __restrict__ outg) {
  const int bh = blockIdx.x, qt = 31 - blockIdx.y;
  const int b = bh >> 4, h = bh & 15;
  const int tid = threadIdx.x, w = tid >> 6, l = tid & 63;
  const int lr = l & 15, lg = l >> 4;

  __shared__ unsigned short Ks[64 * 72];     // [key][d]
  __shared__ unsigned short Vs[64 * 72];     // [d][key]
  __shared__ unsigned short Ps[4][16 * 72];  // per-wave P tile [qrow][key]

  const int qrow0 = qt * 64 + w * 16;
  const float QSCALE = 0.125f * 1.44269504089f;  // 1/sqrt(dh) * log2(e)

  bf16x8 qf[2];
#pragma unroll
  for (int s = 0; s < 2; ++s) {
    bf16x8 raw = *(const bf16x8*)&qg[(size_t)(b * 2048 + qrow0 + lr) * 1152 + h * 64 + s * 32 + lg * 8];
#pragma unroll
    for (int j = 0; j < 8; ++j)
      raw[j] = (short)f2bf(bf2f((unsigned short)raw[j]) * QSCALE);
    qf[s] = raw;
  }

  f32x4 acc[4] = {};
  float m_i[4], l_i[4];
#pragma unroll
  for (int i = 0; i < 4; ++i) { m_i[i] = -1e30f; l_i[i] = 0.f; }

  // prologue: stage tile 0
  bf16x8 kreg[2], vreg[2];
#pragma unroll
  for (int it = 0; it < 2; ++it) {
    int slot = it * 256 + tid, row = slot >> 3, c8 = (slot & 7) * 8;
    kreg[it] = *(const bf16x8*)&kvg[(size_t)(b * 2048 + row) * 2048 + h * 64 + c8];
    vreg[it] = *(const bf16x8*)&vtg[((size_t)(bh * 64 + row)) * 2048 + c8];
  }
#pragma unroll
  for (int it = 0; it < 2; ++it) {
    int slot = it * 256 + tid, row = slot >> 3, c8 = (slot & 7) * 8;
    *(bf16x8*)&Ks[row * 72 + c8] = kreg[it];
    *(bf16x8*)&Vs[row * 72 + c8] = vreg[it];
  }
  __syncthreads();

  for (int kt = 0; kt <= qt; ++kt) {
    // T14 async-stage: issue next tile's global loads now, ds_write after post-PV barrier
    if (kt < qt) {
#pragma unroll
      for (int it = 0; it < 2; ++it) {
        int slot = it * 256 + tid, row = slot >> 3, c8 = (slot & 7) * 8;
        kreg[it] = *(const bf16x8*)&kvg[(size_t)(b * 2048 + (kt + 1) * 64 + row) * 2048 + h * 64 + c8];
        vreg[it] = *(const bf16x8*)&vtg[((size_t)(bh * 64 + row)) * 2048 + (kt + 1) * 64 + c8];
      }
    }

    // S = Q K^T (log2 domain); C-layout: col=key=lr, row=lg*4+i
    f32x4 s[4];
    __builtin_amdgcn_s_setprio(1);
#pragma unroll
    for (int n = 0; n < 4; ++n) {
      f32x4 z = {};
#pragma unroll
      for (int ks = 0; ks < 2; ++ks) {
        bf16x8 kf = *(const bf16x8*)&Ks[(n * 16 + lr) * 72 + ks * 32 + lg * 8];
        z = __builtin_amdgcn_mfma_f32_16x16x32_bf16(qf[ks], kf, z, 0, 0, 0);
      }
      s[n] = z;
    }
    __builtin_amdgcn_s_setprio(0);

    // key-mask bias + (diagonal only) causal mask; per-row max
    float bs[4];
#pragma unroll
    for (int n = 0; n < 4; ++n) bs[n] = biasg[b * 2048 + kt * 64 + n * 16 + lr];

    float p[4][4];
    float mx[4] = {-1e30f, -1e30f, -1e30f, -1e30f};
    if (kt == qt) {
#pragma unroll
      for (int n = 0; n < 4; ++n) {
        int key = kt * 64 + n * 16 + lr;
#pragma unroll
        for (int i = 0; i < 4; ++i) {
          float v = s[n][i] + bs[n];
          v = (key <= qrow0 + lg * 4 + i) ? v : -1e30f;
          p[n][i] = v;
          mx[i] = fmaxf(mx[i], v);
        }
      }
    } else {
#pragma unroll
      for (int n = 0; n < 4; ++n)
#pragma unroll
        for (int i = 0; i < 4; ++i) {
          float v = s[n][i] + bs[n];
          p[n][i] = v;
          mx[i] = fmaxf(mx[i], v);
        }
    }
    // cross-lane row max over lr (16 contiguous lanes) via DPP butterfly
#pragma unroll
    for (int i = 0; i < 4; ++i) mx[i] = rowmax16(mx[i]);

    // T13 defer-rescale (THR=8 in log2 domain)
    float g = fmaxf(fmaxf(mx[0] - m_i[0], mx[1] - m_i[1]),
                    fmaxf(mx[2] - m_i[2], mx[3] - m_i[3]));
    if (__any(g > 8.0f)) {
#pragma unroll
      for (int i = 0; i < 4; ++i) {
        float mn = fmaxf(m_i[i], mx[i]);
        float sc = fexp2(m_i[i] - mn);
        m_i[i] = mn;
        l_i[i] *= sc;
#pragma unroll
        for (int dt = 0; dt < 4; ++dt) acc[dt][i] *= sc;
      }
    }

    float rs[4] = {0.f, 0.f, 0.f, 0.f};
#pragma unroll
    for (int n = 0; n < 4; ++n)
#pragma unroll
      for (int i = 0; i < 4; ++i) {
        float e = fexp2(p[n][i] - m_i[i]);
        p[n][i] = e;
        rs[i] += e;
      }
    // cross-lane row sum via DPP butterfly
#pragma unroll
    for (int i = 0; i < 4; ++i) l_i[i] += rowsum16(rs[i]);

    // P -> per-wave LDS (cvt_pk pairs), wave-synchronous
#pragma unroll
    for (int n = 0; n < 4; ++n)
#pragma unroll
      for (int i2 = 0; i2 < 4; i2 += 2) {
        unsigned rr;
        asm("v_cvt_pk_bf16_f32 %0, %1, %2" : "=v"(rr) : "v"(p[n][i2]), "v"(p[n][i2 + 1]));
        Ps[w][(lg * 4 + i2) * 72 + n * 16 + lr] = (unsigned short)rr;
        Ps[w][(lg * 4 + i2 + 1) * 72 + n * 16 + lr] = (unsigned short)(rr >> 16);
      }
    asm volatile("s_waitcnt lgkmcnt(0)" ::: "memory");

    // O += P V
    __builtin_amdgcn_s_setprio(1);
#pragma unroll
    for (int ks = 0; ks < 2; ++ks) {
      bf16x8 pf = *(const bf16x8*)&Ps[w][lr * 72 + ks * 32 + lg * 8];
#pragma unroll
      for (int dt = 0; dt < 4; ++dt) {
        bf16x8 vf = *(const bf16x8*)&Vs[(dt * 16 + lr) * 72 + ks * 32 + lg * 8];
        acc[dt] = __builtin_amdgcn_mfma_f32_16x16x32_bf16(pf, vf, acc[dt], 0, 0, 0);
      }
    }
    __builtin_amdgcn_s_setprio(0);

    __syncthreads();
    if (kt < qt) {
#pragma unroll
      for (int it = 0; it < 2; ++it) {
        int slot = it * 256 + tid, row = slot >> 3, c8 = (slot & 7) * 8;
        *(bf16x8*)&Ks[row * 72 + c8] = kreg[it];
        *(bf16x8*)&Vs[row * 72 + c8] = vreg[it];
      }
      __syncthreads();
    }
  }

  float inv[4];
#pragma unroll
  for (int i = 0; i < 4; ++i) inv[i] = 1.f / l_i[i];
#pragma unroll
  for (int dt = 0; dt < 4; ++dt)
#pragma unroll
    for (int i = 0; i < 4; ++i)
      outg[(size_t)(b * 2048 + qrow0 + lg * 4 + i) * 1024 + h * 64 + dt * 16 + lr] =
          acc[dt][i] * inv[i];
}

// ---------- launch ----------
extern "C" void kernel_launch(void* const* d_in, const int* in_sizes, int n_in,
                              void* d_out, int out_size, void* d_ws, size_t ws_size,
                              hipStream_t stream) {
  const float* x    = (const float*)d_in[0];
  const int*   mask = (const int*)d_in[1];
  const float* w_q  = (const float*)d_in[2];
  const float* w_d  = (const float*)d_in[3];
  const float* w_k  = (const float*)d_in[4];
  const float* w_v  = (const float*)d_in[5];
  float* out = (float*)d_out;

  char* ws = (char*)d_ws;
  size_t off = 0;
  auto alloc = [&](size_t elems) {
    unsigned short* p = (unsigned short*)(ws + off);
    off += ((elems * 2 + 255) & ~(size_t)255);
    return p;
  };
  unsigned short* x_bf = alloc(4194304);      // [4096][1024]
  unsigned short* wqdt = alloc(1152 * 1024);  // [1152][1024]
  unsigned short* wkvt = alloc(2048 * 128);   // [2048][128]
  unsigned short* qlat = alloc(4096 * 1152);  // [4096][1152]: q | latent
  unsigned short* kv   = alloc(4096 * 2048);  // [4096][2048]: k | v
  unsigned short* vt   = alloc(4194304);      // [32][64][2048]
  float* bias = (float*)alloc(8192);          // 4096 floats

  prep_kernel<<<2448, 256, 0, stream>>>(x, mask, w_q, w_d, w_k, w_v, x_bf, wqdt, wkvt, bias);

  gemm_bt<<<dim3(32, 9), 256, 0, stream>>>(x_bf, 1024, wqdt, 1024, qlat, 1152, 1024);
  gemm_bt<<<dim3(32, 16), 256, 0, stream>>>(qlat + 1024, 1152, wkvt, 128, kv, 2048, 128);

  vt_kernel<<<dim3(32, 64, 2), 256, 0, stream>>>(kv, vt);
  attn_kernel<<<dim3(32, 32), 256, 0, stream>>>(qlat, kv, vt, bias, out);
}

// Round 7
// 89.917 us; speedup vs baseline: 1.9673x; 1.0971x over previous
//
#include <hip/hip_runtime.h>

// ---------- types & helpers ----------
typedef __attribute__((ext_vector_type(8))) short bf16x8;
typedef __attribute__((ext_vector_type(4))) float f32x4;

__device__ inline unsigned short f2bf(float f) {
  unsigned u = __builtin_bit_cast(unsigned, f);
  unsigned r = u + 0x7FFFu + ((u >> 16) & 1u);
  return (unsigned short)(r >> 16);
}
__device__ inline float bf2f(unsigned short s) {
  unsigned u = ((unsigned)s) << 16;
  return __builtin_bit_cast(float, u);
}
__device__ inline float fexp2(float x) { return __builtin_amdgcn_exp2f(x); }

__device__ inline void gload_lds16(const unsigned short* g, unsigned short* l) {
  __builtin_amdgcn_global_load_lds(
      (const __attribute__((address_space(1))) unsigned int*)g,
      (__attribute__((address_space(3))) unsigned int*)l, 16, 0, 0);
}

// ---------- fused preprocessing: x->bf16, 4 weight transposes, mask bias + tileok ----------
__global__ __launch_bounds__(256) void prep_kernel(
    const float* __restrict__ x, const int* __restrict__ mask,
    const float* __restrict__ w_q, const float* __restrict__ w_d,
    const float* __restrict__ w_k, const float* __restrict__ w_v,
    unsigned short* __restrict__ x_bf, unsigned short* __restrict__ wqdt,
    unsigned short* __restrict__ wkvt, float* __restrict__ bias,
    int* __restrict__ tileok) {
  int bid = blockIdx.x;
  if (bid < 1024) {  // x fp32 -> bf16, 4096 elems/block
    int base = bid * 4096 + threadIdx.x * 4;
#pragma unroll
    for (int it = 0; it < 4; ++it) {
      int idx = base + it * 1024;
      float4 v = *(const float4*)&x[idx];
      ushort4 o;
      o.x = f2bf(v.x); o.y = f2bf(v.y); o.z = f2bf(v.z); o.w = f2bf(v.w);
      *(ushort4*)&x_bf[idx] = o;
    }
    return;
  }
  int tb = bid - 1024;
  if (tb >= 1408) {  // mask -> additive bias + per-64-key-tile all-valid flag
    int i = (tb - 1408) * 256 + threadIdx.x;
    int mv = mask[i];
    bias[i] = mv ? 0.0f : -1e30f;
    int ok = __all(mv != 0);  // each wave covers exactly one aligned 64-key tile
    if ((threadIdx.x & 63) == 0) tileok[i >> 6] = ok;
    return;
  }
  const float* in; unsigned short* out; int R, C, tr, tc;
  if (tb < 1024)      { in = w_q; out = wqdt;               R = 1024; C = 1024; tr = tb >> 5; tc = tb & 31; }
  else if (tb < 1152) { int t2 = tb - 1024; in = w_d; out = wqdt + 1024 * 1024; R = 1024; C = 128; tr = t2 >> 2; tc = t2 & 3; }
  else if (tb < 1280) { int t2 = tb - 1152; in = w_k; out = wkvt;               R = 128; C = 1024; tr = t2 >> 5; tc = t2 & 31; }
  else                { int t2 = tb - 1280; in = w_v; out = wkvt + 1024 * 128;  R = 128; C = 1024; tr = t2 >> 5; tc = t2 & 31; }
  __shared__ float t[32][33];
  int r0 = tr * 32, c0 = tc * 32;
  int tx = threadIdx.x & 31, ty = threadIdx.x >> 5;
  for (int r = ty; r < 32; r += 8)
    t[r][tx] = in[(size_t)(r0 + r) * C + c0 + tx];
  __syncthreads();
  for (int cc = ty; cc < 32; cc += 8)
    out[(size_t)(c0 + cc) * R + r0 + tx] = f2bf(t[tx][cc]);
}

// ---------- per-head V transpose: kv[b*T+t][1024+h*64+d] -> vt[(bh*64+d)][t] ----------
__global__ __launch_bounds__(256) void vt_kernel(const unsigned short* __restrict__ kv,
                                                 unsigned short* __restrict__ vt) {
  int bh = blockIdx.x, tt = blockIdx.y, dt = blockIdx.z;
  int b = bh >> 4, h = bh & 15;
  __shared__ unsigned short tile[32][33];
  int tx = threadIdx.x & 31, ty = threadIdx.x >> 5;
  for (int r = ty; r < 32; r += 8)
    tile[r][tx] = kv[(size_t)(b * 2048 + tt * 32 + r) * 2048 + 1024 + h * 64 + dt * 32 + tx];
  __syncthreads();
  for (int r = ty; r < 32; r += 8)
    vt[((size_t)(bh * 64 + dt * 32 + r)) * 2048 + tt * 32 + tx] = tile[tx][r];
}

// ---------- GEMM: C[M][N] = A[M][K] * Bt[N][K]^T, bf16 in/out, fp32 accum ----------
// M-tile 128, N-tile BN (128 or 64). 4 waves.
template <int BN>
__global__ __launch_bounds__(256) void gemm_bt(const unsigned short* __restrict__ A, int lda,
                                               const unsigned short* __restrict__ Bt, int ldb,
                                               unsigned short* __restrict__ C, int ldc,
                                               int K) {
  constexpr int WM = (BN == 128) ? 2 : 4;  // waves along M
  constexpr int WN = 4 / WM;               // waves along N
  constexpr int MR = 128 / WM / 16;        // m-frags per wave
  constexpr int NR = BN / WN / 16;         // n-frags per wave
  constexpr int RPW = 128 / WM;            // rows per wave (M)
  constexpr int CPW = BN / WN;             // cols per wave (N)
  __shared__ unsigned short As[128 * 32];
  __shared__ unsigned short Bs[BN * 32];
  int m0 = blockIdx.x * 128, n0 = blockIdx.y * BN;
  int tid = threadIdx.x, w = tid >> 6, l = tid & 63;
  int lr = l & 15, lg = l >> 4;
  int wr = w / WN, wc = w % WN;
  f32x4 acc[MR][NR] = {};

  for (int k0 = 0; k0 < K; k0 += 32) {
    __syncthreads();
#pragma unroll
    for (int it = 0; it < 2; ++it) {
      int c = w * 2 + it;
      int row = c * 16 + (l >> 2);
      int col = (l & 3) * 8;
      gload_lds16(&A[(size_t)(m0 + row) * lda + k0 + col], &As[c * 512 + l * 8]);
    }
    if constexpr (BN == 128) {
#pragma unroll
      for (int it = 0; it < 2; ++it) {
        int c = w * 2 + it;
        int row = c * 16 + (l >> 2);
        int col = (l & 3) * 8;
        gload_lds16(&Bt[(size_t)(n0 + row) * ldb + k0 + col], &Bs[c * 512 + l * 8]);
      }
    } else {
      int row = w * 16 + (l >> 2);
      int col = (l & 3) * 8;
      gload_lds16(&Bt[(size_t)(n0 + row) * ldb + k0 + col], &Bs[w * 512 + l * 8]);
    }
    __syncthreads();
    bf16x8 af[MR], bfr[NR];
#pragma unroll
    for (int m = 0; m < MR; ++m)
      af[m] = *(const bf16x8*)&As[(wr * RPW + m * 16 + lr) * 32 + lg * 8];
#pragma unroll
    for (int n = 0; n < NR; ++n)
      bfr[n] = *(const bf16x8*)&Bs[(wc * CPW + n * 16 + lr) * 32 + lg * 8];
    __builtin_amdgcn_s_setprio(1);
#pragma unroll
    for (int m = 0; m < MR; ++m)
#pragma unroll
      for (int n = 0; n < NR; ++n)
        acc[m][n] = __builtin_amdgcn_mfma_f32_16x16x32_bf16(af[m], bfr[n], acc[m][n], 0, 0, 0);
    __builtin_amdgcn_s_setprio(0);
  }

#pragma unroll
  for (int m = 0; m < MR; ++m)
#pragma unroll
    for (int n = 0; n < NR; ++n)
#pragma unroll
      for (int i = 0; i < 4; ++i)
        C[(size_t)(m0 + wr * RPW + m * 16 + lg * 4 + i) * ldc + n0 + wc * CPW + n * 16 + lr] =
            f2bf(acc[m][n][i]);
}

// ---------- flash attention: swapped QK^T, lane-local softmax, exp2 domain ----------
// grid (bh=32, y=32), qt = 31 - y. 4 waves, wave w owns q rows qt*64+w*16 .. +15.
// S^T = mfma(K,Q): lane (lr,lg) holds row qrow0+lr, keys kt*64 + n*16 + lg*4 + i.
__global__ __launch_bounds__(256) void attn_kernel(const unsigned short* __restrict__ qg,
                                                   const unsigned short* __restrict__ kvg,
                                                   const unsigned short* __restrict__ vtg,
                                                   const float* __restrict__ biasg,
                                                   const int* __restrict__ tileokg,
                                                   float* __restrict__ outg) {
  const int bh = blockIdx.x, qt = 31 - blockIdx.y;
  const int b = bh >> 4, h = bh & 15;
  const int tid = threadIdx.x, w = tid >> 6, l = tid & 63;
  const int lr = l & 15, lg = l >> 4;

  __shared__ unsigned short Ks[64 * 72];     // [key][d]
  __shared__ unsigned short Vs[64 * 72];     // [d][key]
  __shared__ unsigned short Ps[4][16 * 72];  // per-wave P tile [qrow][key]

  const int qrow0 = qt * 64 + w * 16;
  const float QSCALE = 0.125f * 1.44269504089f;  // 1/sqrt(dh) * log2(e)

  bf16x8 qf[2];
#pragma unroll
  for (int s = 0; s < 2; ++s) {
    bf16x8 raw = *(const bf16x8*)&qg[(size_t)(b * 2048 + qrow0 + lr) * 1152 + h * 64 + s * 32 + lg * 8];
#pragma unroll
    for (int j = 0; j < 8; ++j)
      raw[j] = (short)f2bf(bf2f((unsigned short)raw[j]) * QSCALE);
    qf[s] = raw;
  }

  f32x4 acc[4] = {};
  float m_i = -1e30f;   // running max for row qrow0+lr (this lane's row)
  float l_part = 0.f;   // per-lane partial denominator for row qrow0+lr

  // prologue: stage tile 0
  bf16x8 kreg[2], vreg[2];
#pragma unroll
  for (int it = 0; it < 2; ++it) {
    int slot = it * 256 + tid, row = slot >> 3, c8 = (slot & 7) * 8;
    kreg[it] = *(const bf16x8*)&kvg[(size_t)(b * 2048 + row) * 2048 + h * 64 + c8];
    vreg[it] = *(const bf16x8*)&vtg[((size_t)(bh * 64 + row)) * 2048 + c8];
  }
#pragma unroll
  for (int it = 0; it < 2; ++it) {
    int slot = it * 256 + tid, row = slot >> 3, c8 = (slot & 7) * 8;
    *(bf16x8*)&Ks[row * 72 + c8] = kreg[it];
    *(bf16x8*)&Vs[row * 72 + c8] = vreg[it];
  }
  __syncthreads();

  for (int kt = 0; kt <= qt; ++kt) {
    // T14 async-stage: issue next tile's global loads now, ds_write after post-PV barrier
    if (kt < qt) {
#pragma unroll
      for (int it = 0; it < 2; ++it) {
        int slot = it * 256 + tid, row = slot >> 3, c8 = (slot & 7) * 8;
        kreg[it] = *(const bf16x8*)&kvg[(size_t)(b * 2048 + (kt + 1) * 64 + row) * 2048 + h * 64 + c8];
        vreg[it] = *(const bf16x8*)&vtg[((size_t)(bh * 64 + row)) * 2048 + (kt + 1) * 64 + c8];
      }
    }

    // S^T = K Q^T: D col=lr (qrow), row=key_local = n*16 + lg*4 + i
    f32x4 s[4];
    __builtin_amdgcn_s_setprio(1);
#pragma unroll
    for (int n = 0; n < 4; ++n) {
      f32x4 z = {};
#pragma unroll
      for (int ks = 0; ks < 2; ++ks) {
        bf16x8 kf = *(const bf16x8*)&Ks[(n * 16 + lr) * 72 + ks * 32 + lg * 8];
        z = __builtin_amdgcn_mfma_f32_16x16x32_bf16(kf, qf[ks], z, 0, 0, 0);
      }
      s[n] = z;
    }
    __builtin_amdgcn_s_setprio(0);

    const int tok = tileokg[b * 32 + kt];
    float p[4][4];
    float mx = -1e30f;
    if (tok) {
      if (kt == qt) {
#pragma unroll
        for (int n = 0; n < 4; ++n)
#pragma unroll
          for (int i = 0; i < 4; ++i) {
            float v = (n * 16 + lg * 4 + i <= w * 16 + lr) ? s[n][i] : -1e30f;
            p[n][i] = v;
            mx = fmaxf(mx, v);
          }
      } else {
#pragma unroll
        for (int n = 0; n < 4; ++n)
#pragma unroll
          for (int i = 0; i < 4; ++i) {
            p[n][i] = s[n][i];
            mx = fmaxf(mx, s[n][i]);
          }
      }
    } else {  // rare general-mask path
#pragma unroll
      for (int n = 0; n < 4; ++n)
#pragma unroll
        for (int i = 0; i < 4; ++i) {
          int keyl = n * 16 + lg * 4 + i;
          float v = s[n][i] + biasg[b * 2048 + kt * 64 + keyl];
          if (kt == qt) v = (keyl <= w * 16 + lr) ? v : -1e30f;
          p[n][i] = v;
          mx = fmaxf(mx, v);
        }
    }
    // cross-lane max over the 4 lg-groups holding this row's other keys
    mx = fmaxf(mx, __shfl_xor(mx, 16, 64));
    mx = fmaxf(mx, __shfl_xor(mx, 32, 64));

    // T13 defer-rescale (THR=8 in log2 domain)
    if (__any(mx - m_i > 8.0f)) {
      float mn = fmaxf(m_i, mx);
      float sc = fexp2(m_i - mn);
      m_i = mn;
      l_part *= sc;
      float scb[4];
#pragma unroll
      for (int i = 0; i < 4; ++i) scb[i] = __shfl(sc, lg * 4 + i, 64);
#pragma unroll
      for (int dt = 0; dt < 4; ++dt)
#pragma unroll
        for (int i = 0; i < 4; ++i) acc[dt][i] *= scb[i];
    }

    float rs = 0.f;
#pragma unroll
    for (int n = 0; n < 4; ++n)
#pragma unroll
      for (int i = 0; i < 4; ++i) {
        float e = fexp2(p[n][i] - m_i);
        p[n][i] = e;
        rs += e;
      }
    l_part += rs;  // cross-lane l reduction deferred to epilogue

    // P -> per-wave LDS: 8 b32 writes (adjacent keys packed via cvt_pk)
#pragma unroll
    for (int n = 0; n < 4; ++n) {
      unsigned r0, r1;
      asm("v_cvt_pk_bf16_f32 %0, %1, %2" : "=v"(r0) : "v"(p[n][0]), "v"(p[n][1]));
      asm("v_cvt_pk_bf16_f32 %0, %1, %2" : "=v"(r1) : "v"(p[n][2]), "v"(p[n][3]));
      *(unsigned*)&Ps[w][lr * 72 + n * 16 + lg * 4]     = r0;
      *(unsigned*)&Ps[w][lr * 72 + n * 16 + lg * 4 + 2] = r1;
    }
    asm volatile("s_waitcnt lgkmcnt(0)" ::: "memory");

    // O += P V  (A-frag: row=lr=qrow, k=key; unchanged layout)
    __builtin_amdgcn_s_setprio(1);
#pragma unroll
    for (int ks = 0; ks < 2; ++ks) {
      bf16x8 pf = *(const bf16x8*)&Ps[w][lr * 72 + ks * 32 + lg * 8];
#pragma unroll
      for (int dt = 0; dt < 4; ++dt) {
        bf16x8 vf = *(const bf16x8*)&Vs[(dt * 16 + lr) * 72 + ks * 32 + lg * 8];
        acc[dt] = __builtin_amdgcn_mfma_f32_16x16x32_bf16(pf, vf, acc[dt], 0, 0, 0);
      }
    }
    __builtin_amdgcn_s_setprio(0);

    __syncthreads();
    if (kt < qt) {
#pragma unroll
      for (int it = 0; it < 2; ++it) {
        int slot = it * 256 + tid, row = slot >> 3, c8 = (slot & 7) * 8;
        *(bf16x8*)&Ks[row * 72 + c8] = kreg[it];
        *(bf16x8*)&Vs[row * 72 + c8] = vreg[it];
      }
      __syncthreads();
    }
  }

  // epilogue: finish l reduction (lanes lr, lr+16, lr+32, lr+48 hold row lr's partials)
  float lt = l_part;
  lt += __shfl_xor(lt, 16, 64);
  lt += __shfl_xor(lt, 32, 64);
  float inv = 1.f / lt;  // inverse denom for row qrow0+lr
  float invb[4];
#pragma unroll
  for (int i = 0; i < 4; ++i) invb[i] = __shfl(inv, lg * 4 + i, 64);
#pragma unroll
  for (int dt = 0; dt < 4; ++dt)
#pragma unroll
    for (int i = 0; i < 4; ++i)
      outg[(size_t)(b * 2048 + qrow0 + lg * 4 + i) * 1024 + h * 64 + dt * 16 + lr] =
          acc[dt][i] * invb[i];
}

// ---------- launch ----------
extern "C" void kernel_launch(void* const* d_in, const int* in_sizes, int n_in,
                              void* d_out, int out_size, void* d_ws, size_t ws_size,
                              hipStream_t stream) {
  const float* x    = (const float*)d_in[0];
  const int*   mask = (const int*)d_in[1];
  const float* w_q  = (const float*)d_in[2];
  const float* w_d  = (const float*)d_in[3];
  const float* w_k  = (const float*)d_in[4];
  const float* w_v  = (const float*)d_in[5];
  float* out = (float*)d_out;

  char* ws = (char*)d_ws;
  size_t off = 0;
  auto alloc = [&](size_t elems) {
    unsigned short* p = (unsigned short*)(ws + off);
    off += ((elems * 2 + 255) & ~(size_t)255);
    return p;
  };
  unsigned short* x_bf = alloc(4194304);      // [4096][1024]
  unsigned short* wqdt = alloc(1152 * 1024);  // [1152][1024]
  unsigned short* wkvt = alloc(2048 * 128);   // [2048][128]
  unsigned short* qlat = alloc(4096 * 1152);  // [4096][1152]: q | latent
  unsigned short* kv   = alloc(4096 * 2048);  // [4096][2048]: k | v
  unsigned short* vt   = alloc(4194304);      // [32][64][2048]
  float* bias = (float*)alloc(8192);          // 4096 floats
  int* tileok = (int*)alloc(128);             // 64 ints

  prep_kernel<<<2448, 256, 0, stream>>>(x, mask, w_q, w_d, w_k, w_v, x_bf, wqdt, wkvt, bias, tileok);

  gemm_bt<64><<<dim3(32, 18), 256, 0, stream>>>(x_bf, 1024, wqdt, 1024, qlat, 1152, 1024);
  gemm_bt<128><<<dim3(32, 16), 256, 0, stream>>>(qlat + 1024, 1152, wkvt, 128, kv, 2048, 128);

  vt_kernel<<<dim3(32, 64, 2), 256, 0, stream>>>(kv, vt);
  attn_kernel<<<dim3(32, 32), 256, 0, stream>>>(qlat, kv, vt, bias, tileok, out);
}